// Round 1
// baseline (339.378 us; speedup 1.0000x reference)
//
#include <hip/hip_runtime.h>

// NTuple approximator evaluation:
// out[b] = sum_{s=0}^{31} weights[table_ids[s], base16(boards[b, sym_coords[s,:]])]
// B = 65536 boards, 32 symmetries, 6 coords each, weights = 4 x 16^6 fp32 (256 MB).
// Random-gather bound: 2M 4B gathers over 256 MB -> L2-miss / L3-hit regime.

static constexpr int NSYM = 32;
static constexpr int TLEN = 6;

__global__ __launch_bounds__(256) void ntuple_eval_kernel(
    const int* __restrict__ boards,
    const float* __restrict__ weights,
    const int* __restrict__ sym_coords,
    const int* __restrict__ table_ids,
    float* __restrict__ out, int B)
{
    __shared__ int s_coords[NSYM * TLEN];
    __shared__ int s_base[NSYM];

    const int t = threadIdx.x;
    if (t < NSYM * TLEN) s_coords[t] = sym_coords[t];
    if (t < NSYM)        s_base[t]   = table_ids[t] << 24;  // * 16^6
    __syncthreads();

    const int b = blockIdx.x * blockDim.x + t;
    if (b >= B) return;

    // Load the 16 board cells with 4x int4 (64 B / thread).
    const int4* bp = reinterpret_cast<const int4*>(boards + (size_t)b * 16);
    const int4 r0 = bp[0], r1 = bp[1], r2 = bp[2], r3 = bp[3];

    // Pack 16 nibbles into one uint64 so coordinate lookup is a variable
    // 64-bit shift (register-only; avoids runtime-indexed array -> scratch).
    const int c[16] = {r0.x, r0.y, r0.z, r0.w,
                       r1.x, r1.y, r1.z, r1.w,
                       r2.x, r2.y, r2.z, r2.w,
                       r3.x, r3.y, r3.z, r3.w};
    unsigned long long packed = 0ull;
#pragma unroll
    for (int i = 0; i < 16; ++i)
        packed |= (unsigned long long)((unsigned)c[i] & 15u) << (4 * i);

    float acc = 0.0f;
#pragma unroll
    for (int s = 0; s < NSYM; ++s) {
        int feat = 0;
#pragma unroll
        for (int j = 0; j < TLEN; ++j) {
            const int cc = s_coords[s * TLEN + j];          // wave-uniform LDS broadcast
            feat = (feat << 4) | (int)((packed >> (cc << 2)) & 15ull);
        }
        acc += weights[(size_t)(s_base[s] + feat)];          // 32 independent gathers
    }
    out[b] = acc;
}

extern "C" void kernel_launch(void* const* d_in, const int* in_sizes, int n_in,
                              void* d_out, int out_size, void* d_ws, size_t ws_size,
                              hipStream_t stream) {
    const int*   boards     = (const int*)d_in[0];
    const float* weights    = (const float*)d_in[1];
    const int*   sym_coords = (const int*)d_in[2];
    const int*   table_ids  = (const int*)d_in[3];
    float*       out        = (float*)d_out;

    const int B = in_sizes[0] / 16;
    const int block = 256;
    const int grid = (B + block - 1) / block;
    ntuple_eval_kernel<<<grid, block, 0, stream>>>(boards, weights, sym_coords,
                                                   table_ids, out, B);
}